// Round 9
// baseline (2296.490 us; speedup 1.0000x reference)
//
#include <hip/hip_runtime.h>

#define H_ 128
#define T_ 1024
#define B_ 512
#define I_ 13
#define LOG2E 1.4426950408889634f

typedef _Float16 half8 __attribute__((ext_vector_type(8)));
typedef float float4_ __attribute__((ext_vector_type(4)));

static __device__ __forceinline__ float fast_rcp(float v) {
  return __builtin_amdgcn_rcpf(v);
}
static __device__ __forceinline__ float fast_exp2(float v) {
  return __builtin_amdgcn_exp2f(v);
}
static __device__ __forceinline__ float sigmoid_f(float v) {
  return fast_rcp(1.0f + fast_exp2(-LOG2E * v));
}
static __device__ __forceinline__ float tanh_f(float v) {
  return 2.0f * fast_rcp(1.0f + fast_exp2(-2.0f * LOG2E * v)) - 1.0f;
}

// R14 = R13 (615us) + three fills/cuts on the measured stall components:
//  (1) balanced FC: waves 0-3 each do ONE partial FC MFMA (kc = wave) and
//      ds_add_f32 the 7 logits into lgring (pre-seeded with b_fc in phase
//      0). Removes the SIMD3 straggler (wave 7 had +4 MFMA = +78cy/step)
//      and FC's 4-deep chain.
//  (2) head fill: seed + x-preacc of tiles 1,3 moved post-barrier (only
//      needs register af4) -> fills the ~150cy ds_read(h) window. Tiles
//      0,2 stay in the tail as its MFMA filler (R11 failed by moving ALL).
//  (3) trans overlap: ladder split ti{0,2} (i,g) then ti{1,3} (f,o);
//      sigmoid(i), tanh(g) computed between halves so ~half the
//      transcendental latency hides under half2's MFMA issue (the
//      sibling wave on the SIMD covers the brief in-order stall).
// Structure: 256 WGs x 8 waves, 2 rows/WG, 2 waves/SIMD, weights
// VGPR-resident, zero vector-memory ops in the loop.
__global__ __launch_bounds__(512, 1) void lstm_fused(
    const float* __restrict__ x, const float* __restrict__ Wih,
    const float* __restrict__ Whh, const float* __restrict__ bih,
    const float* __restrict__ bhh, const float* __restrict__ Wfc,
    const float* __restrict__ bfc, float* __restrict__ out)
{
  // 64 KB: x(t) for both rows (f16), slots 13..15 zero (pad to k-chunk)
  __shared__ __align__(16) _Float16 xlds[T_][2][16];
  // 64 KB: logits ring, slot t = bias + 4 wave-partials (cols 0..6)
  __shared__ __align__(16) float lgring[T_][2][8];
  // 1.3 KB: double-buffered h (cols 0..127 used; stride 168 halfs)
  __shared__ __align__(16) _Float16 abuf[2][2][168];

  const int tid  = threadIdx.x;
  const int wave = tid >> 6;      // 0..7
  const int lane = tid & 63;
  const int n16  = lane & 15;
  const int quad = lane >> 4;
  const int wgb  = blockIdx.x * 2;

  // ---- W fragments: wave w owns tiles {g*8 + w : g=0..3} ----
  // (all 4 gates for col-group w -> cell update is lane-local)
  // B layout (16x16x32): lane holds B[k = quad*8 + j][n = n16]
  half8 wfrag[4][5];
  float biasv[4];
  #pragma unroll
  for (int ti = 0; ti < 4; ++ti) {
    const int tile = ti * 8 + wave;
    const int col  = tile * 16 + n16;
    biasv[ti] = bih[col] + bhh[col];
    #pragma unroll
    for (int kc = 0; kc < 5; ++kc) {
      half8 f;
      #pragma unroll
      for (int j = 0; j < 8; ++j) {
        const int k = kc * 32 + quad * 8 + j;
        float v = 0.0f;
        if (k < 128)            v = Whh[col * H_ + k];
        else if (k < 128 + I_)  v = Wih[col * I_ + (k - 128)];
        f[j] = (_Float16)v;
      }
      wfrag[ti][kc] = f;
    }
  }
  // FC chunk for this wave: wave w (w<4) contributes kc=w partial
  half8 wfcw;
  {
    const int kcw = wave & 3;
    half8 f;
    #pragma unroll
    for (int j = 0; j < 8; ++j) {
      const int k = kcw * 32 + quad * 8 + j;
      f[j] = (_Float16)((n16 < 7) ? Wfc[n16 * H_ + k] : 0.0f);
    }
    wfcw = f;
  }

  // ---- phase 0: preload x into LDS; seed lgring with b_fc; zero abuf ----
  for (int idx = tid; idx < T_ * 2 * 16; idx += 512) {
    const int t  = idx >> 5;
    const int rw = (idx >> 4) & 1;
    const int ii = idx & 15;
    float v = 0.0f;
    if (ii < I_) v = x[((size_t)t * B_ + wgb + rw) * I_ + ii];
    xlds[t][rw][ii] = (_Float16)v;
  }
  for (int idx = tid; idx < T_ * 2 * 8; idx += 512) {
    const int t = idx >> 4;
    const int b = (idx >> 3) & 1;
    const int k = idx & 7;
    lgring[t][b][k] = (k < 7) ? bfc[k] : 0.0f;
  }
  for (int idx = tid; idx < 2 * 2 * 168; idx += 512)
    ((_Float16*)abuf)[idx] = (_Float16)0.0f;
  __syncthreads();

  // cell state: quad q tracks D row 4q: rows 0,8 = batch 0; 4,12 = batch 1
  // (rows 8,12 are duplicates -> quads 2,3 mirror quads 0,1)
  float c_state = 0.0f;
  const bool aload = (n16 & 3) == 0;   // A rows 0,4,8,12
  const int  arow  = (n16 >> 2) & 1;   // rows 0,8 <- b0; 4,12 <- b1

  half8 af[4];
  half8 af4;
  {
    half8 z;
    #pragma unroll
    for (int j = 0; j < 8; ++j) z[j] = (_Float16)0.0f;
    #pragma unroll
    for (int kc = 0; kc < 4; ++kc) af[kc] = z;
    af4 = z;
  }
  if (aload && quad < 2)
    af4 = *(const half8*)&xlds[0][arow][quad * 8];

  float4_ acc[4];
  #pragma unroll
  for (int ti = 0; ti < 4; ++ti)
    #pragma unroll
    for (int r = 0; r < 4; ++r) acc[ti][r] = 0.0f;

  // prologue: seed + x-preacc for tiles 0,2 only (1,3 done at loop top)
  acc[0][0] = biasv[0];
  acc[2][0] = biasv[2];
  acc[0] = __builtin_amdgcn_mfma_f32_16x16x32_f16(af4, wfrag[0][4], acc[0], 0, 0, 0);
  acc[2] = __builtin_amdgcn_mfma_f32_16x16x32_f16(af4, wfrag[2][4], acc[2], 0, 0, 0);

  // ---- phase 1: the recurrence. No vector-memory ops in this loop. ----
  for (int t = 0; t <= T_; ++t) {
    // A fragments: h chunks 0..3 from abuf (issue first)
    if (aload) {
      #pragma unroll
      for (int kc = 0; kc < 4; ++kc)
        af[kc] = *(const half8*)&abuf[t & 1][arow][kc * 32 + quad * 8];
    }

    if (t < T_) {
      // (2) head fill: seed + x-preacc tiles 1,3 -- af4 is a register,
      // so these 2 MFMAs drop into the ds_read latency window.
      acc[1][0] = biasv[1];
      acc[3][0] = biasv[3];
      acc[1] = __builtin_amdgcn_mfma_f32_16x16x32_f16(af4, wfrag[1][4], acc[1], 0, 0, 0);
      acc[3] = __builtin_amdgcn_mfma_f32_16x16x32_f16(af4, wfrag[3][4], acc[3], 0, 0, 0);
    }

    // (1) balanced FC: waves 0-3 each add one kc-partial of the logits.
    if (wave < 4 && t >= 1) {
      float4_ accf;
      #pragma unroll
      for (int r = 0; r < 4; ++r) accf[r] = 0.0f;
      accf = __builtin_amdgcn_mfma_f32_16x16x32_f16(af[wave], wfcw, accf, 0, 0, 0);
      if (lane < 32 && n16 < 7)
        atomicAdd(&lgring[t - 1][quad][n16], accf[0]);
    }

    if (t < T_) {
      // (3) half1: tiles 0 (gate i) and 2 (gate g), kc-inner
      #pragma unroll
      for (int kc = 0; kc < 4; ++kc) {
        acc[0] = __builtin_amdgcn_mfma_f32_16x16x32_f16(af[kc], wfrag[0][kc], acc[0], 0, 0, 0);
        acc[2] = __builtin_amdgcn_mfma_f32_16x16x32_f16(af[kc], wfrag[2][kc], acc[2], 0, 0, 0);
      }
      // early activations for i,g -- exp/rcp latency hides under half2
      // (the sibling wave on this SIMD covers the in-order stall)
      const float iv = sigmoid_f(acc[0][0]);
      const float gg = tanh_f(acc[2][0]);
      // half2: tiles 1 (gate f) and 3 (gate o)
      #pragma unroll
      for (int kc = 0; kc < 4; ++kc) {
        acc[1] = __builtin_amdgcn_mfma_f32_16x16x32_f16(af[kc], wfrag[1][kc], acc[1], 0, 0, 0);
        acc[3] = __builtin_amdgcn_mfma_f32_16x16x32_f16(af[kc], wfrag[3][kc], acc[3], 0, 0, 0);
      }

      // prefetch next x-fragment (independent; hides under activations)
      if (aload && quad < 2 && t + 1 < T_)
        af4 = *(const half8*)&xlds[t + 1][arow][quad * 8];

      // finish cell update (fully lane-local; dup D rows for quads 2,3)
      const float fv = sigmoid_f(acc[1][0]);
      const float ov = sigmoid_f(acc[3][0]);
      c_state = fv * c_state + iv * gg;
      const float hv = ov * tanh_f(c_state);
      if (lane < 32)
        abuf[(t + 1) & 1][quad][16 * wave + n16] = (_Float16)hv;

      // tail filler: seed + x-preacc tiles 0,2 for step t+1
      acc[0][0] = biasv[0];
      acc[2][0] = biasv[2];
      acc[0] = __builtin_amdgcn_mfma_f32_16x16x32_f16(af4, wfrag[0][4], acc[0], 0, 0, 0);
      acc[2] = __builtin_amdgcn_mfma_f32_16x16x32_f16(af4, wfrag[2][4], acc[2], 0, 0, 0);
    }

    __syncthreads();
  }

  // ---- phase 2: softmax of all 2048 logit rows -> out ----
  for (int r = tid; r < T_ * 2; r += 512) {
    const int t = r >> 1;
    const int b = r & 1;
    float lg[7];
    float mx = -3.0e38f;
    #pragma unroll
    for (int k = 0; k < 7; ++k) {
      lg[k] = lgring[t][b][k];
      mx = fmaxf(mx, lg[k]);
    }
    float s = 0.0f;
    #pragma unroll
    for (int k = 0; k < 7; ++k) {
      lg[k] = fast_exp2(LOG2E * (lg[k] - mx));
      s += lg[k];
    }
    const float rs = fast_rcp(s);
    float* op = &out[((size_t)t * B_ + wgb + b) * 7];
    #pragma unroll
    for (int k = 0; k < 7; ++k) op[k] = lg[k] * rs;
  }
}

extern "C" void kernel_launch(void* const* d_in, const int* in_sizes, int n_in,
                              void* d_out, int out_size, void* d_ws, size_t ws_size,
                              hipStream_t stream) {
  (void)in_sizes; (void)n_in; (void)out_size; (void)d_ws; (void)ws_size;
  const float* x   = (const float*)d_in[0];
  const float* Wih = (const float*)d_in[1];
  const float* Whh = (const float*)d_in[2];
  const float* bih = (const float*)d_in[3];
  const float* bhh = (const float*)d_in[4];
  const float* Wfc = (const float*)d_in[5];
  const float* bfc = (const float*)d_in[6];
  hipLaunchKernelGGL(lstm_fused, dim3(256), dim3(512), 0, stream,
                     x, Wih, Whh, bih, bhh, Wfc, bfc, (float*)d_out);
}

// Round 10
// 657.898 us; speedup vs baseline: 3.4906x; 3.4906x over previous
//
#include <hip/hip_runtime.h>

#define H_ 128
#define T_ 1024
#define B_ 512
#define I_ 13
#define LOG2E 1.4426950408889634f

typedef _Float16 half8 __attribute__((ext_vector_type(8)));
typedef float float4_ __attribute__((ext_vector_type(4)));

static __device__ __forceinline__ float fast_rcp(float v) {
  return __builtin_amdgcn_rcpf(v);
}
static __device__ __forceinline__ float fast_exp2(float v) {
  return __builtin_amdgcn_exp2f(v);
}
static __device__ __forceinline__ float sigmoid_f(float v) {
  return fast_rcp(1.0f + fast_exp2(-LOG2E * v));
}
static __device__ __forceinline__ float tanh_f(float v) {
  return 2.0f * fast_rcp(1.0f + fast_exp2(-2.0f * LOG2E * v)) - 1.0f;
}

// R15 = R13 (615us) + head-fill + trans-overlap ONLY.
// R14 post-mortem: the 3.7x regression was change (1) -- shared-float
// atomicAdd lowers to a contended CAS loop (4 waves x same 14 addrs,
// ~120cy LDS round trip per retry) and af[wave] runtime indexing forces
// select-chain extraction (rule #20). FC reverted to R13's wave-7 form.
// Kept (isolated this time):
//  (2) head fill: seed + x-preacc of tiles 1,3 post-barrier -- they
//      depend only on register af4, so the 2 MFMAs slot into the ~150cy
//      ds_read(h) window where every af-consumer is stalled. Tiles 0,2
//      stay in the tail as its filler (R11: never move ALL of it).
//  (3) trans overlap: ladder split {i,g} -> sigmoid/tanh -> {f,o};
//      ~half the transcendental latency hides under half2's MFMA issue
//      (sibling wave on the SIMD covers the brief in-order stall).
// Structure: 256 WGs x 8 waves, 2 rows/WG, 2 waves/SIMD, weights
// VGPR-resident, zero vector-memory ops in the loop.
__global__ __launch_bounds__(512, 1) void lstm_fused(
    const float* __restrict__ x, const float* __restrict__ Wih,
    const float* __restrict__ Whh, const float* __restrict__ bih,
    const float* __restrict__ bhh, const float* __restrict__ Wfc,
    const float* __restrict__ bfc, float* __restrict__ out)
{
  // 64 KB: x(t) for both rows (f16), slots 13..15 zero (pad to k-chunk)
  __shared__ __align__(16) _Float16 xlds[T_][2][16];
  // 64 KB: logits ring, slot t holds logits for output row t (cols 0..6)
  __shared__ __align__(16) float lgring[T_][2][8];
  // 1.3 KB: double-buffered h (cols 0..127 used; stride 168 halfs)
  __shared__ __align__(16) _Float16 abuf[2][2][168];

  const int tid  = threadIdx.x;
  const int wave = tid >> 6;      // 0..7
  const int lane = tid & 63;
  const int n16  = lane & 15;
  const int quad = lane >> 4;
  const int wgb  = blockIdx.x * 2;

  // ---- W fragments: wave w owns tiles {g*8 + w : g=0..3} ----
  // (all 4 gates for col-group w -> cell update is lane-local)
  // B layout (16x16x32): lane holds B[k = quad*8 + j][n = n16]
  half8 wfrag[4][5];
  float biasv[4];
  #pragma unroll
  for (int ti = 0; ti < 4; ++ti) {
    const int tile = ti * 8 + wave;
    const int col  = tile * 16 + n16;
    biasv[ti] = bih[col] + bhh[col];
    #pragma unroll
    for (int kc = 0; kc < 5; ++kc) {
      half8 f;
      #pragma unroll
      for (int j = 0; j < 8; ++j) {
        const int k = kc * 32 + quad * 8 + j;
        float v = 0.0f;
        if (k < 128)            v = Whh[col * H_ + k];
        else if (k < 128 + I_)  v = Wih[col * I_ + (k - 128)];
        f[j] = (_Float16)v;
      }
      wfrag[ti][kc] = f;
    }
  }
  // FC tile (consumed by wave 7; loaded uniformly), k < 128 -> 4 chunks
  half8 wfc[4];
  const float biasfc = (n16 < 7) ? bfc[n16] : 0.0f;
  #pragma unroll
  for (int kc = 0; kc < 4; ++kc) {
    half8 f;
    #pragma unroll
    for (int j = 0; j < 8; ++j) {
      const int k = kc * 32 + quad * 8 + j;
      f[j] = (_Float16)((n16 < 7) ? Wfc[n16 * H_ + k] : 0.0f);
    }
    wfc[kc] = f;
  }

  // ---- phase 0: preload all x for this WG into LDS (f16), zero pads ----
  for (int idx = tid; idx < T_ * 2 * 16; idx += 512) {
    const int t  = idx >> 5;
    const int rw = (idx >> 4) & 1;
    const int ii = idx & 15;
    float v = 0.0f;
    if (ii < I_) v = x[((size_t)t * B_ + wgb + rw) * I_ + ii];
    xlds[t][rw][ii] = (_Float16)v;
  }
  for (int idx = tid; idx < 2 * 2 * 168; idx += 512)
    ((_Float16*)abuf)[idx] = (_Float16)0.0f;
  __syncthreads();

  // cell state: quad q tracks D row 4q: rows 0,8 = batch 0; 4,12 = batch 1
  // (rows 8,12 are duplicates -> quads 2,3 mirror quads 0,1)
  float c_state = 0.0f;
  const bool aload = (n16 & 3) == 0;   // A rows 0,4,8,12
  const int  arow  = (n16 >> 2) & 1;   // rows 0,8 <- b0; 4,12 <- b1

  half8 af[4];
  half8 af4;
  {
    half8 z;
    #pragma unroll
    for (int j = 0; j < 8; ++j) z[j] = (_Float16)0.0f;
    #pragma unroll
    for (int kc = 0; kc < 4; ++kc) af[kc] = z;
    af4 = z;
  }
  if (aload && quad < 2)
    af4 = *(const half8*)&xlds[0][arow][quad * 8];

  float4_ acc[4];
  #pragma unroll
  for (int ti = 0; ti < 4; ++ti)
    #pragma unroll
    for (int r = 0; r < 4; ++r) acc[ti][r] = 0.0f;
  float4_ accf;
  #pragma unroll
  for (int r = 0; r < 4; ++r) accf[r] = 0.0f;

  // prologue: seed + x-preacc tiles 0,2 only (1,3 done at loop head)
  acc[0][0] = biasv[0];
  acc[2][0] = biasv[2];
  acc[0] = __builtin_amdgcn_mfma_f32_16x16x32_f16(af4, wfrag[0][4], acc[0], 0, 0, 0);
  acc[2] = __builtin_amdgcn_mfma_f32_16x16x32_f16(af4, wfrag[2][4], acc[2], 0, 0, 0);

  // ---- phase 1: the recurrence. No vector-memory ops in this loop. ----
  for (int t = 0; t <= T_; ++t) {
    // A fragments: h chunks 0..3 from abuf (issue first)
    if (aload) {
      #pragma unroll
      for (int kc = 0; kc < 4; ++kc)
        af[kc] = *(const half8*)&abuf[t & 1][arow][kc * 32 + quad * 8];
    }

    if (t < T_) {
      // (2) head fill: seed + x-preacc tiles 1,3 -- af4 is a register,
      // so these 2 MFMAs issue inside the ds_read latency window.
      acc[1][0] = biasv[1];
      acc[3][0] = biasv[3];
      acc[1] = __builtin_amdgcn_mfma_f32_16x16x32_f16(af4, wfrag[1][4], acc[1], 0, 0, 0);
      acc[3] = __builtin_amdgcn_mfma_f32_16x16x32_f16(af4, wfrag[3][4], acc[3], 0, 0, 0);
    }

    // FC logits (wave 7, R13 proven form): first af consumer; its 4-deep
    // chain drains under the gate ladder.
    if (wave == 7 && t >= 1) {
      accf[0] = biasfc;
      #pragma unroll
      for (int kc = 0; kc < 4; ++kc)
        accf = __builtin_amdgcn_mfma_f32_16x16x32_f16(af[kc], wfc[kc], accf, 0, 0, 0);
      if (lane < 32 && n16 < 7)
        lgring[t - 1][quad][n16] = accf[0];
    }

    if (t < T_) {
      // (3) half1: tiles 0 (gate i) and 2 (gate g), kc-inner
      #pragma unroll
      for (int kc = 0; kc < 4; ++kc) {
        acc[0] = __builtin_amdgcn_mfma_f32_16x16x32_f16(af[kc], wfrag[0][kc], acc[0], 0, 0, 0);
        acc[2] = __builtin_amdgcn_mfma_f32_16x16x32_f16(af[kc], wfrag[2][kc], acc[2], 0, 0, 0);
      }
      // early activations for i,g -- their exp/rcp latency hides under
      // half2's MFMA issue (sibling wave covers the in-order stall)
      const float iv = sigmoid_f(acc[0][0]);
      const float gg = tanh_f(acc[2][0]);
      const float ig = iv * gg;
      // half2: tiles 1 (gate f) and 3 (gate o)
      #pragma unroll
      for (int kc = 0; kc < 4; ++kc) {
        acc[1] = __builtin_amdgcn_mfma_f32_16x16x32_f16(af[kc], wfrag[1][kc], acc[1], 0, 0, 0);
        acc[3] = __builtin_amdgcn_mfma_f32_16x16x32_f16(af[kc], wfrag[3][kc], acc[3], 0, 0, 0);
      }

      // prefetch next x-fragment (independent; hides under activations)
      if (aload && quad < 2 && t + 1 < T_)
        af4 = *(const half8*)&xlds[t + 1][arow][quad * 8];

      // finish cell update (fully lane-local; dup D rows for quads 2,3)
      const float fv = sigmoid_f(acc[1][0]);
      const float ov = sigmoid_f(acc[3][0]);
      c_state = fv * c_state + ig;
      const float hv = ov * tanh_f(c_state);
      if (lane < 32)
        abuf[(t + 1) & 1][quad][16 * wave + n16] = (_Float16)hv;

      // tail filler: seed + x-preacc tiles 0,2 for step t+1
      acc[0][0] = biasv[0];
      acc[2][0] = biasv[2];
      acc[0] = __builtin_amdgcn_mfma_f32_16x16x32_f16(af4, wfrag[0][4], acc[0], 0, 0, 0);
      acc[2] = __builtin_amdgcn_mfma_f32_16x16x32_f16(af4, wfrag[2][4], acc[2], 0, 0, 0);
    }

    __syncthreads();
  }

  // ---- phase 2: softmax of all 2048 logit rows -> out ----
  for (int r = tid; r < T_ * 2; r += 512) {
    const int t = r >> 1;
    const int b = r & 1;
    float lg[7];
    float mx = -3.0e38f;
    #pragma unroll
    for (int k = 0; k < 7; ++k) {
      lg[k] = lgring[t][b][k];
      mx = fmaxf(mx, lg[k]);
    }
    float s = 0.0f;
    #pragma unroll
    for (int k = 0; k < 7; ++k) {
      lg[k] = fast_exp2(LOG2E * (lg[k] - mx));
      s += lg[k];
    }
    const float rs = fast_rcp(s);
    float* op = &out[((size_t)t * B_ + wgb + b) * 7];
    #pragma unroll
    for (int k = 0; k < 7; ++k) op[k] = lg[k] * rs;
  }
}

extern "C" void kernel_launch(void* const* d_in, const int* in_sizes, int n_in,
                              void* d_out, int out_size, void* d_ws, size_t ws_size,
                              hipStream_t stream) {
  (void)in_sizes; (void)n_in; (void)out_size; (void)d_ws; (void)ws_size;
  const float* x   = (const float*)d_in[0];
  const float* Wih = (const float*)d_in[1];
  const float* Whh = (const float*)d_in[2];
  const float* bih = (const float*)d_in[3];
  const float* bhh = (const float*)d_in[4];
  const float* Wfc = (const float*)d_in[5];
  const float* bfc = (const float*)d_in[6];
  hipLaunchKernelGGL(lstm_fused, dim3(256), dim3(512), 0, stream,
                     x, Wih, Whh, bih, bhh, Wfc, bfc, (float*)d_out);
}

// Round 11
// 637.428 us; speedup vs baseline: 3.6027x; 1.0321x over previous
//
#include <hip/hip_runtime.h>

#define H_ 128
#define T_ 1024
#define B_ 512
#define I_ 13
#define LOG2E 1.4426950408889634f

typedef _Float16 half8 __attribute__((ext_vector_type(8)));
typedef float float4_ __attribute__((ext_vector_type(4)));

static __device__ __forceinline__ float fast_rcp(float v) {
  return __builtin_amdgcn_rcpf(v);
}
static __device__ __forceinline__ float fast_exp2(float v) {
  return __builtin_amdgcn_exp2f(v);
}
static __device__ __forceinline__ float sigmoid_f(float v) {
  return fast_rcp(1.0f + fast_exp2(-LOG2E * v));
}
static __device__ __forceinline__ float tanh_f(float v) {
  return 2.0f * fast_rcp(1.0f + fast_exp2(-2.0f * LOG2E * v)) - 1.0f;
}

// R16 = R13 (615us) + head-fill ONLY (completes the R15 A/B).
// R15 post-mortem: the i/g-early-activation split (3) serialized the
// ladder -- the in-order wave had to wait for acc[0]/acc[2] chain drain
// mid-stream before issuing half2 (+~100cy/step). Reverted: ladder is
// R13's kc-outer x ti-inner full interleave, activations all at the end.
// Kept (isolated):
//  (2) head fill: seed + x-preacc of tiles 1,3 at the loop head -- they
//      depend only on register af4, so the 2 MFMAs issue inside the
//      ~150cy ds_read(h) window where every af-consumer is stalled.
//      Tiles 0,2 stay in the tail as the MFMA filler under the
//      activation VALU (R11: the tail filler must stay).
// Structure: 256 WGs x 8 waves, 2 rows/WG, 2 waves/SIMD, weights
// VGPR-resident, zero vector-memory ops in the loop.
__global__ __launch_bounds__(512, 1) void lstm_fused(
    const float* __restrict__ x, const float* __restrict__ Wih,
    const float* __restrict__ Whh, const float* __restrict__ bih,
    const float* __restrict__ bhh, const float* __restrict__ Wfc,
    const float* __restrict__ bfc, float* __restrict__ out)
{
  // 64 KB: x(t) for both rows (f16), slots 13..15 zero (pad to k-chunk)
  __shared__ __align__(16) _Float16 xlds[T_][2][16];
  // 64 KB: logits ring, slot t holds logits for output row t (cols 0..6)
  __shared__ __align__(16) float lgring[T_][2][8];
  // 1.3 KB: double-buffered h (cols 0..127 used; stride 168 halfs)
  __shared__ __align__(16) _Float16 abuf[2][2][168];

  const int tid  = threadIdx.x;
  const int wave = tid >> 6;      // 0..7
  const int lane = tid & 63;
  const int n16  = lane & 15;
  const int quad = lane >> 4;
  const int wgb  = blockIdx.x * 2;

  // ---- W fragments: wave w owns tiles {g*8 + w : g=0..3} ----
  // (all 4 gates for col-group w -> cell update is lane-local)
  // B layout (16x16x32): lane holds B[k = quad*8 + j][n = n16]
  half8 wfrag[4][5];
  float biasv[4];
  #pragma unroll
  for (int ti = 0; ti < 4; ++ti) {
    const int tile = ti * 8 + wave;
    const int col  = tile * 16 + n16;
    biasv[ti] = bih[col] + bhh[col];
    #pragma unroll
    for (int kc = 0; kc < 5; ++kc) {
      half8 f;
      #pragma unroll
      for (int j = 0; j < 8; ++j) {
        const int k = kc * 32 + quad * 8 + j;
        float v = 0.0f;
        if (k < 128)            v = Whh[col * H_ + k];
        else if (k < 128 + I_)  v = Wih[col * I_ + (k - 128)];
        f[j] = (_Float16)v;
      }
      wfrag[ti][kc] = f;
    }
  }
  // FC tile (consumed by wave 7; loaded uniformly), k < 128 -> 4 chunks
  half8 wfc[4];
  const float biasfc = (n16 < 7) ? bfc[n16] : 0.0f;
  #pragma unroll
  for (int kc = 0; kc < 4; ++kc) {
    half8 f;
    #pragma unroll
    for (int j = 0; j < 8; ++j) {
      const int k = kc * 32 + quad * 8 + j;
      f[j] = (_Float16)((n16 < 7) ? Wfc[n16 * H_ + k] : 0.0f);
    }
    wfc[kc] = f;
  }

  // ---- phase 0: preload all x for this WG into LDS (f16), zero pads ----
  for (int idx = tid; idx < T_ * 2 * 16; idx += 512) {
    const int t  = idx >> 5;
    const int rw = (idx >> 4) & 1;
    const int ii = idx & 15;
    float v = 0.0f;
    if (ii < I_) v = x[((size_t)t * B_ + wgb + rw) * I_ + ii];
    xlds[t][rw][ii] = (_Float16)v;
  }
  for (int idx = tid; idx < 2 * 2 * 168; idx += 512)
    ((_Float16*)abuf)[idx] = (_Float16)0.0f;
  __syncthreads();

  // cell state: quad q tracks D row 4q: rows 0,8 = batch 0; 4,12 = batch 1
  // (rows 8,12 are duplicates -> quads 2,3 mirror quads 0,1)
  float c_state = 0.0f;
  const bool aload = (n16 & 3) == 0;   // A rows 0,4,8,12
  const int  arow  = (n16 >> 2) & 1;   // rows 0,8 <- b0; 4,12 <- b1

  half8 af[4];
  half8 af4;
  {
    half8 z;
    #pragma unroll
    for (int j = 0; j < 8; ++j) z[j] = (_Float16)0.0f;
    #pragma unroll
    for (int kc = 0; kc < 4; ++kc) af[kc] = z;
    af4 = z;
  }
  if (aload && quad < 2)
    af4 = *(const half8*)&xlds[0][arow][quad * 8];

  float4_ acc[4];
  #pragma unroll
  for (int ti = 0; ti < 4; ++ti)
    #pragma unroll
    for (int r = 0; r < 4; ++r) acc[ti][r] = 0.0f;
  float4_ accf;
  #pragma unroll
  for (int r = 0; r < 4; ++r) accf[r] = 0.0f;

  // prologue: seed + x-preacc tiles 0,2 only (1,3 done at loop head)
  acc[0][0] = biasv[0];
  acc[2][0] = biasv[2];
  acc[0] = __builtin_amdgcn_mfma_f32_16x16x32_f16(af4, wfrag[0][4], acc[0], 0, 0, 0);
  acc[2] = __builtin_amdgcn_mfma_f32_16x16x32_f16(af4, wfrag[2][4], acc[2], 0, 0, 0);

  // ---- phase 1: the recurrence. No vector-memory ops in this loop. ----
  for (int t = 0; t <= T_; ++t) {
    // A fragments: h chunks 0..3 from abuf (issue first)
    if (aload) {
      #pragma unroll
      for (int kc = 0; kc < 4; ++kc)
        af[kc] = *(const half8*)&abuf[t & 1][arow][kc * 32 + quad * 8];
    }

    if (t < T_) {
      // head fill: seed + x-preacc tiles 1,3 -- af4 is a register, so
      // these 2 MFMAs issue inside the ds_read latency window.
      acc[1][0] = biasv[1];
      acc[3][0] = biasv[3];
      acc[1] = __builtin_amdgcn_mfma_f32_16x16x32_f16(af4, wfrag[1][4], acc[1], 0, 0, 0);
      acc[3] = __builtin_amdgcn_mfma_f32_16x16x32_f16(af4, wfrag[3][4], acc[3], 0, 0, 0);
    }

    // FC logits (wave 7): first af consumer; its 4-deep chain drains
    // under the gate ladder.
    if (wave == 7 && t >= 1) {
      accf[0] = biasfc;
      #pragma unroll
      for (int kc = 0; kc < 4; ++kc)
        accf = __builtin_amdgcn_mfma_f32_16x16x32_f16(af[kc], wfc[kc], accf, 0, 0, 0);
      if (lane < 32 && n16 < 7)
        lgring[t - 1][quad][n16] = accf[0];
    }

    if (t < T_) {
      // h-dependent ladder: R13's full interleave (kc outer, ti inner) --
      // all 16 MFMAs issue back-to-back; no mid-stream dependent VALU.
      #pragma unroll
      for (int kc = 0; kc < 4; ++kc) {
        #pragma unroll
        for (int ti = 0; ti < 4; ++ti)
          acc[ti] = __builtin_amdgcn_mfma_f32_16x16x32_f16(af[kc], wfrag[ti][kc], acc[ti], 0, 0, 0);
      }

      // prefetch next x-fragment (independent; hides under activations)
      if (aload && quad < 2 && t + 1 < T_)
        af4 = *(const half8*)&xlds[t + 1][arow][quad * 8];

      // cell update, FULL wave, fully lane-local (dup D rows quads 2,3)
      const float iv = sigmoid_f(acc[0][0]);
      const float fv = sigmoid_f(acc[1][0]);
      const float gg = tanh_f(acc[2][0]);
      const float ov = sigmoid_f(acc[3][0]);
      c_state = fv * c_state + iv * gg;
      const float hv = ov * tanh_f(c_state);
      if (lane < 32)
        abuf[(t + 1) & 1][quad][16 * wave + n16] = (_Float16)hv;

      // tail filler: seed + x-preacc tiles 0,2 for step t+1 (keeps the
      // MFMA pipe busy under the activation VALU / barrier wait)
      acc[0][0] = biasv[0];
      acc[2][0] = biasv[2];
      acc[0] = __builtin_amdgcn_mfma_f32_16x16x32_f16(af4, wfrag[0][4], acc[0], 0, 0, 0);
      acc[2] = __builtin_amdgcn_mfma_f32_16x16x32_f16(af4, wfrag[2][4], acc[2], 0, 0, 0);
    }

    __syncthreads();
  }

  // ---- phase 2: softmax of all 2048 logit rows -> out ----
  for (int r = tid; r < T_ * 2; r += 512) {
    const int t = r >> 1;
    const int b = r & 1;
    float lg[7];
    float mx = -3.0e38f;
    #pragma unroll
    for (int k = 0; k < 7; ++k) {
      lg[k] = lgring[t][b][k];
      mx = fmaxf(mx, lg[k]);
    }
    float s = 0.0f;
    #pragma unroll
    for (int k = 0; k < 7; ++k) {
      lg[k] = fast_exp2(LOG2E * (lg[k] - mx));
      s += lg[k];
    }
    const float rs = fast_rcp(s);
    float* op = &out[((size_t)t * B_ + wgb + b) * 7];
    #pragma unroll
    for (int k = 0; k < 7; ++k) op[k] = lg[k] * rs;
  }
}

extern "C" void kernel_launch(void* const* d_in, const int* in_sizes, int n_in,
                              void* d_out, int out_size, void* d_ws, size_t ws_size,
                              hipStream_t stream) {
  (void)in_sizes; (void)n_in; (void)out_size; (void)d_ws; (void)ws_size;
  const float* x   = (const float*)d_in[0];
  const float* Wih = (const float*)d_in[1];
  const float* Whh = (const float*)d_in[2];
  const float* bih = (const float*)d_in[3];
  const float* bhh = (const float*)d_in[4];
  const float* Wfc = (const float*)d_in[5];
  const float* bfc = (const float*)d_in[6];
  hipLaunchKernelGGL(lstm_fused, dim3(256), dim3(512), 0, stream,
                     x, Wih, Whh, bih, bhh, Wfc, bfc, (float*)d_out);
}